// Round 5
// baseline (182.209 us; speedup 1.0000x reference)
//
#include <hip/hip_runtime.h>
#include <hip/hip_bf16.h>

// Problem constants (from reference)
#define BATCH      8
#define S_BYTES    8192
#define NUM_EMB    384
#define BYTE_DIM   128
#define EMB_DIM    1024
#define NUM_TOKENS 2048
#define SCALE_F    11.313708498984761f   // sqrt(128)

#define M_TOTAL (BATCH * NUM_TOKENS)     // 16384 rows into the GEMM
#define SEG_STRIDE 2064                  // 2049 entries padded

typedef __bf16 bf16x8 __attribute__((ext_vector_type(8)));
typedef float  floatx4 __attribute__((ext_vector_type(4)));

// ---------------------------------------------------------------------------
// Kernel A (fused): blockIdx < 256  -> segment-boundary precompute
//                   blockIdx >= 256 -> out_proj_w fp32 -> bf16 convert
// Boundary: bg rows sorted; thread (b,i) writes seg[b][t]=i for t in
// (bg[i-1], bg[i]]; thread i==S-1 fills the tail. Each entry written once.
// ---------------------------------------------------------------------------
__global__ __launch_bounds__(256) void prep_kernel(
    const int* __restrict__ bg,           // [B, S_BYTES] sorted per row
    int* __restrict__ seg,                // [B, SEG_STRIDE]
    const float* __restrict__ w,          // [EMB_DIM, BYTE_DIM] fp32
    __hip_bfloat16* __restrict__ wb)      // [EMB_DIM, BYTE_DIM] bf16
{
    if (blockIdx.x < 256) {
        const int gid = blockIdx.x * 256 + threadIdx.x;   // 0..65535
        const int b = gid >> 13;
        const int i = gid & (S_BYTES - 1);
        const int g  = bg[gid];
        const int gp = (i == 0) ? -1 : bg[gid - 1];
        int* __restrict__ srow = seg + b * SEG_STRIDE;
        for (int t = gp + 1; t <= g; ++t) srow[t] = i;
        if (i == S_BYTES - 1) {
            for (int t = g + 1; t <= NUM_TOKENS; ++t) srow[t] = S_BYTES;
        }
    } else {
        const int i = ((blockIdx.x - 256) * 256 + threadIdx.x) * 4;  // 128 blocks
        const float4 v = *(const float4*)(w + i);
        wb[i + 0] = __float2bfloat16(v.x);
        wb[i + 1] = __float2bfloat16(v.y);
        wb[i + 2] = __float2bfloat16(v.z);
        wb[i + 3] = __float2bfloat16(v.w);
    }
}

// ---------------------------------------------------------------------------
// Kernel B (fused pool + GEMM): grid = 256 blocks = 128 mb x 2 halves.
// Each block:
//  1. pools its 128-token A-tile byte-parallel: for each byte i in the tile's
//     range, 128 d-lanes atomicAdd emb[x[i]][d] into fp32 LDS row bg[i]-t0.
//     (sorted bg -> concurrent collisions are ~2-way; LDS ds_add is cheap)
//  2. converts to bf16 (mean * sqrt(128)) into the MFMA A-tile
//  3. runs 4 N-tiles of the m97-style 128x128 MFMA GEMM (half 0: nb 0-3,
//     half 1: nb 4-7), fp32 scattered stores.
// LDS: 64 KB acc + 32 KB A + 32 KB B -> 1 block/CU, grid 256 = 1 per CU.
// A-frag: A[m = lane&15][k = quad*8 + j]; C/D: col = lane&15, row = quad*4+reg.
// ---------------------------------------------------------------------------
__global__ __launch_bounds__(256) void pool_gemm_kernel(
    const int* __restrict__ x,                 // [B, S_BYTES]
    const int* __restrict__ bg,                // [B, S_BYTES]
    const int* __restrict__ seg,               // [B, SEG_STRIDE]
    const float* __restrict__ emb,             // [NUM_EMB, BYTE_DIM] fp32
    const __hip_bfloat16* __restrict__ wb,     // [EMB_DIM, BYTE_DIM] bf16
    float* __restrict__ out)                   // [M_TOTAL, EMB_DIM] fp32
{
    __shared__ float          sAacc[128 * 128];   // 64 KB fp32 accumulators
    __shared__ __hip_bfloat16 sAb[128 * 128];     // 32 KB MFMA A-tile
    __shared__ __hip_bfloat16 sB[128 * 128];      // 32 KB MFMA B-tile
    __shared__ int            sseg[129];

    const int mb   = blockIdx.x & 127;   // fast -> round-robins mb over XCDs
    const int half = blockIdx.x >> 7;    // 0: nb 0-3, 1: nb 4-7
    const int b    = mb >> 4;
    const int t0   = (mb & 15) << 7;     // first token of this M-tile
    const int tid  = threadIdx.x;
    const int d    = tid & 127;
    const int slot = tid >> 7;           // 2 byte-slots

    // ---- zero accumulators, stage segment bounds ----
    {
        float4* z = (float4*)sAacc;
        #pragma unroll
        for (int i = 0; i < 16; ++i) z[tid + i * 256] = float4{0.f, 0.f, 0.f, 0.f};
    }
    if (tid < 129) sseg[tid] = seg[b * SEG_STRIDE + t0 + tid];
    __syncthreads();

    // ---- byte-parallel pooling ----
    {
        const int s0 = sseg[0], s1 = sseg[128];
        const int* __restrict__ xrow = x + b * S_BYTES;
        const int* __restrict__ grow = bg + b * S_BYTES;
        #pragma unroll 4
        for (int i = s0 + slot; i < s1; i += 2) {
            const int e = xrow[i];           // broadcast across the half's lanes
            const int t = grow[i] - t0;      // broadcast
            atomicAdd(&sAacc[t * 128 + d], emb[e * BYTE_DIM + d]);
        }
    }
    __syncthreads();

    // ---- mean * scale, fp32 -> bf16 A-tile ----
    for (int tok = slot; tok < 128; tok += 2) {
        const int cnt = sseg[tok + 1] - sseg[tok];
        const float inv = SCALE_F / (float)(cnt > 1 ? cnt : 1);
        sAb[tok * 128 + d] = __float2bfloat16(sAacc[tok * 128 + d] * inv);
    }
    __syncthreads();

    // ---- GEMM: 4 N-tiles of 128, wave = 64x64 (4x4 subtiles) ----
    const int wave = tid >> 6;
    const int lane = tid & 63;
    const int wm = wave >> 1;        // 0..1
    const int wn = wave & 1;         // 0..1
    const int r    = lane & 15;
    const int quad = lane >> 4;
    const int m0 = mb * 128;

    for (int nbq = 0; nbq < 4; ++nbq) {
        const int n0 = (half * 4 + nbq) * 128;

        // stage B-tile (16384 elems = 2048 x 16B chunks)
        {
            const bf16x8* __restrict__ gB = (const bf16x8*)(wb + (size_t)n0 * BYTE_DIM);
            bf16x8* __restrict__ lB = (bf16x8*)sB;
            #pragma unroll
            for (int i = 0; i < 8; ++i) lB[tid + i * 256] = gB[tid + i * 256];
        }
        __syncthreads();

        floatx4 acc[4][4] = {};
        #pragma unroll
        for (int kk = 0; kk < 4; ++kk) {
            bf16x8 af[4], bfr[4];
            #pragma unroll
            for (int i = 0; i < 4; ++i)
                af[i] = *(const bf16x8*)(sAb + (wm * 64 + i * 16 + r) * BYTE_DIM + kk * 32 + quad * 8);
            #pragma unroll
            for (int j = 0; j < 4; ++j)
                bfr[j] = *(const bf16x8*)(sB + (wn * 64 + j * 16 + r) * BYTE_DIM + kk * 32 + quad * 8);
            #pragma unroll
            for (int i = 0; i < 4; ++i)
                #pragma unroll
                for (int j = 0; j < 4; ++j)
                    acc[i][j] = __builtin_amdgcn_mfma_f32_16x16x32_bf16(af[i], bfr[j], acc[i][j], 0, 0, 0);
        }

        #pragma unroll
        for (int i = 0; i < 4; ++i) {
            const int mrow = m0 + wm * 64 + i * 16 + quad * 4;
            #pragma unroll
            for (int j = 0; j < 4; ++j) {
                const int ncol = n0 + wn * 64 + j * 16 + r;
                float* __restrict__ p = out + (size_t)mrow * EMB_DIM + ncol;
                #pragma unroll
                for (int reg = 0; reg < 4; ++reg)
                    p[(size_t)reg * EMB_DIM] = acc[i][j][reg];
            }
        }
        __syncthreads();   // protect sB before next stage
    }
}

extern "C" void kernel_launch(void* const* d_in, const int* in_sizes, int n_in,
                              void* d_out, int out_size, void* d_ws, size_t ws_size,
                              hipStream_t stream) {
    const int*   x   = (const int*)d_in[0];     // [8, 8192] int32
    const int*   bg  = (const int*)d_in[1];     // [8, 8192] int32 (sorted rows)
    const float* emb = (const float*)d_in[2];   // [384, 128] fp32
    const float* w   = (const float*)d_in[3];   // [1024, 128] fp32
    float*       out = (float*)d_out;           // [16384, 1024] fp32

    // ws layout: wb bf16 [1024,128] (256 KB) | seg int [8][2064]
    __hip_bfloat16* wb  = (__hip_bfloat16*)d_ws;
    int*            seg = (int*)((char*)d_ws + (size_t)EMB_DIM * BYTE_DIM * 2);

    prep_kernel<<<256 + (EMB_DIM * BYTE_DIM) / (256 * 4), 256, 0, stream>>>(bg, seg, w, wb);
    pool_gemm_kernel<<<256, 256, 0, stream>>>(x, bg, seg, emb, wb, out);
}

// Round 6
// 96.738 us; speedup vs baseline: 1.8835x; 1.8835x over previous
//
#include <hip/hip_runtime.h>
#include <hip/hip_bf16.h>

// Problem constants (from reference)
#define BATCH      8
#define S_BYTES    8192
#define NUM_EMB    384
#define BYTE_DIM   128
#define EMB_DIM    1024
#define NUM_TOKENS 2048
#define SCALE_F    11.313708498984761f   // sqrt(128)

#define M_TOTAL (BATCH * NUM_TOKENS)     // 16384 rows into the GEMM
#define SEG_STRIDE 2064                  // 2049 entries padded

typedef __bf16 bf16x8 __attribute__((ext_vector_type(8)));
typedef float  floatx4 __attribute__((ext_vector_type(4)));

// ---------------------------------------------------------------------------
// Kernel A (fused): blockIdx < 256  -> segment-boundary precompute
//                   blockIdx >= 256 -> out_proj_w fp32 -> bf16 convert
// Boundary: bg rows sorted; thread (b,i) writes seg[b][t]=i for t in
// (bg[i-1], bg[i]]; thread i==S-1 fills the tail. Each entry written once.
// ---------------------------------------------------------------------------
__global__ __launch_bounds__(256) void prep_kernel(
    const int* __restrict__ bg,           // [B, S_BYTES] sorted per row
    int* __restrict__ seg,                // [B, SEG_STRIDE]
    const float* __restrict__ w,          // [EMB_DIM, BYTE_DIM] fp32
    __hip_bfloat16* __restrict__ wb)      // [EMB_DIM, BYTE_DIM] bf16
{
    if (blockIdx.x < 256) {
        const int gid = blockIdx.x * 256 + threadIdx.x;   // 0..65535
        const int b = gid >> 13;
        const int i = gid & (S_BYTES - 1);
        const int g  = bg[gid];
        const int gp = (i == 0) ? -1 : bg[gid - 1];
        int* __restrict__ srow = seg + b * SEG_STRIDE;
        for (int t = gp + 1; t <= g; ++t) srow[t] = i;
        if (i == S_BYTES - 1) {
            for (int t = g + 1; t <= NUM_TOKENS; ++t) srow[t] = S_BYTES;
        }
    } else {
        const int i = ((blockIdx.x - 256) * 256 + threadIdx.x) * 4;  // 128 blocks
        const float4 v = *(const float4*)(w + i);
        wb[i + 0] = __float2bfloat16(v.x);
        wb[i + 1] = __float2bfloat16(v.y);
        wb[i + 2] = __float2bfloat16(v.z);
        wb[i + 3] = __float2bfloat16(v.w);
    }
}

// ---------------------------------------------------------------------------
// Kernel B: segment-mean pooling, float4 gathers.
// 4 tokens per 128-thread block: 32 lanes x float4 (16 B) per token row.
// O(1) seg bounds; gather loop iterations independent (unroll 4).
// Writes grouped row as coalesced 8 B per lane (256 B per token).
// ---------------------------------------------------------------------------
__global__ __launch_bounds__(128) void pool_kernel(
    const int* __restrict__ x,                 // [B, S_BYTES]
    const int* __restrict__ seg,               // [B, SEG_STRIDE]
    const float* __restrict__ emb,             // [NUM_EMB, BYTE_DIM] fp32
    __hip_bfloat16* __restrict__ grouped)      // [B*NUM_TOKENS, BYTE_DIM] bf16
{
    const int sub  = threadIdx.x >> 5;         // token slot 0..3
    const int lane = threadIdx.x & 31;         // 32 lanes per token
    const int m    = blockIdx.x * 4 + sub;     // global token row
    const int b    = m >> 11;
    const int t    = m & (NUM_TOKENS - 1);

    const int s   = seg[b * SEG_STRIDE + t];
    const int e   = seg[b * SEG_STRIDE + t + 1];
    const int cnt = e - s;

    const int* __restrict__ xrow = x + b * S_BYTES;
    const float4* __restrict__ embv = (const float4*)emb;   // [NUM_EMB][32]

    float4 sum = {0.f, 0.f, 0.f, 0.f};
    #pragma unroll 4
    for (int i = s; i < e; ++i) {
        const int ei = xrow[i];                // broadcast across the 32 lanes
        const float4 v = embv[ei * 32 + lane]; // 512 B row, 16 B/lane coalesced
        sum.x += v.x; sum.y += v.y; sum.z += v.z; sum.w += v.w;
    }
    const float inv = SCALE_F / (float)(cnt > 1 ? cnt : 1);

    __hip_bfloat16 o[4];
    o[0] = __float2bfloat16(sum.x * inv);
    o[1] = __float2bfloat16(sum.y * inv);
    o[2] = __float2bfloat16(sum.z * inv);
    o[3] = __float2bfloat16(sum.w * inv);
    *(uint2*)(grouped + (size_t)m * BYTE_DIM + lane * 4) = *(const uint2*)o;
}

// ---------------------------------------------------------------------------
// Kernel C: GEMM, m97-style LDS-staged 128x128 block, K=128 (single stage).
// (byte-identical to R4 — known-good 14 us)
// ---------------------------------------------------------------------------
__global__ __launch_bounds__(256) void gemm_kernel(
    const __hip_bfloat16* __restrict__ A,   // [M_TOTAL, 128] bf16
    const __hip_bfloat16* __restrict__ W,   // [EMB_DIM, 128] bf16
    float* __restrict__ out)                // [M_TOTAL, EMB_DIM] fp32
{
    __shared__ __hip_bfloat16 sA[128 * 128];   // 32 KB, [m][k]
    __shared__ __hip_bfloat16 sB[128 * 128];   // 32 KB, [n][k]

    const int mb = blockIdx.x & 127;           // 128 M-blocks (fast -> XCD spread)
    const int nb = blockIdx.x >> 7;            // 8 N-blocks
    const int m0 = mb * 128;
    const int n0 = nb * 128;
    const int tid = threadIdx.x;

    {
        const bf16x8* __restrict__ gA = (const bf16x8*)(A + (size_t)m0 * BYTE_DIM);
        const bf16x8* __restrict__ gB = (const bf16x8*)(W + (size_t)n0 * BYTE_DIM);
        bf16x8* __restrict__ lA = (bf16x8*)sA;
        bf16x8* __restrict__ lB = (bf16x8*)sB;
        #pragma unroll
        for (int i = 0; i < 8; ++i) {
            lA[tid + i * 256] = gA[tid + i * 256];
            lB[tid + i * 256] = gB[tid + i * 256];
        }
    }
    __syncthreads();

    const int wave = tid >> 6;
    const int lane = tid & 63;
    const int wm = wave >> 1;        // 0..1
    const int wn = wave & 1;         // 0..1
    const int r    = lane & 15;
    const int quad = lane >> 4;

    floatx4 acc[4][4] = {};

    #pragma unroll
    for (int kk = 0; kk < 4; ++kk) {
        bf16x8 af[4], bfr[4];
        #pragma unroll
        for (int i = 0; i < 4; ++i)
            af[i] = *(const bf16x8*)(sA + (wm * 64 + i * 16 + r) * BYTE_DIM + kk * 32 + quad * 8);
        #pragma unroll
        for (int j = 0; j < 4; ++j)
            bfr[j] = *(const bf16x8*)(sB + (wn * 64 + j * 16 + r) * BYTE_DIM + kk * 32 + quad * 8);
        #pragma unroll
        for (int i = 0; i < 4; ++i)
            #pragma unroll
            for (int j = 0; j < 4; ++j)
                acc[i][j] = __builtin_amdgcn_mfma_f32_16x16x32_bf16(af[i], bfr[j], acc[i][j], 0, 0, 0);
    }

    #pragma unroll
    for (int i = 0; i < 4; ++i) {
        const int mrow = m0 + wm * 64 + i * 16 + quad * 4;
        #pragma unroll
        for (int j = 0; j < 4; ++j) {
            const int ncol = n0 + wn * 64 + j * 16 + r;
            float* __restrict__ p = out + (size_t)mrow * EMB_DIM + ncol;
            #pragma unroll
            for (int reg = 0; reg < 4; ++reg)
                p[(size_t)reg * EMB_DIM] = acc[i][j][reg];
        }
    }
}

extern "C" void kernel_launch(void* const* d_in, const int* in_sizes, int n_in,
                              void* d_out, int out_size, void* d_ws, size_t ws_size,
                              hipStream_t stream) {
    const int*   x   = (const int*)d_in[0];     // [8, 8192] int32
    const int*   bg  = (const int*)d_in[1];     // [8, 8192] int32 (sorted rows)
    const float* emb = (const float*)d_in[2];   // [384, 128] fp32
    const float* w   = (const float*)d_in[3];   // [1024, 128] fp32
    float*       out = (float*)d_out;           // [16384, 1024] fp32

    // ws layout: grouped bf16 [16384,128] (4 MB) | wb bf16 (256 KB) | seg int [8][2064]
    __hip_bfloat16* grouped = (__hip_bfloat16*)d_ws;
    __hip_bfloat16* wb      = (__hip_bfloat16*)((char*)d_ws + (size_t)M_TOTAL * BYTE_DIM * 2);
    int*            seg     = (int*)((char*)d_ws + (size_t)M_TOTAL * BYTE_DIM * 2
                                                 + (size_t)EMB_DIM * BYTE_DIM * 2);

    prep_kernel<<<256 + (EMB_DIM * BYTE_DIM) / (256 * 4), 256, 0, stream>>>(bg, seg, w, wb);
    pool_kernel<<<M_TOTAL / 4, 128, 0, stream>>>(x, seg, emb, grouped);
    gemm_kernel<<<(M_TOTAL / 128) * (EMB_DIM / 128), 256, 0, stream>>>(grouped, wb, out);
}